// Round 5
// baseline (601.600 us; speedup 1.0000x reference)
//
#include <hip/hip_runtime.h>
#include <stdint.h>

// CoscamLoss: B=4096 rows, C=16384 cols. One block (256 thr) per row.
// loss = mean_rows [ logsumexp_j(v[j]) - v[t] ],
//   v[j] = 16 * ( j==t ? gt-0.1 : (pos[j]==1 && x[j]>=gt) ? 1.012x[j]+0.012 : x[j] )
//
// R4 post-mortem: VGPR-batched loads were EXACTLY neutral vs R3 -> per-CU
// vector-load miss-tracker cap (~5 KB in flight/CU x 900cyc HBM latency
// = 5.8 B/cyc/CU = the observed 3.4 TB/s). R5: stream via global_load_lds
// DMA (own deep vmcnt queue, no VGPR return; the m93->m97 lever). Per-wave
// private LDS ring, DEPTH=4, manual s_waitcnt vmcnt(N) -- no __syncthreads
// in the loop, so no vmcnt(0) barrier drain.
//
// Wait-constant safety: needed DMA #(2k+2) retired <=> outstanding <=
// total_issued - pos. Any compiler-inserted vm ops only increase
// total_issued or pos-shift both sides equally -> threshold >= 6 always;
// waiting vmcnt(6) (tail 6/4/2/0) is always sufficient.
//
// Numerics: shift = max(16*(gt-0.1), 40): overflow needs x > 7.9 (never);
// sum >= representable row-max term; underflow < e^-87 relative. Target slot
// handled by exact epilogue correction.

#define B_ 4096
#define C_ 16384
#define LOG2E 1.44269504088896340736f

// wait until <= n vmem ops outstanding; leave expcnt/lgkmcnt unconstrained
#define WAIT_VM(n) __builtin_amdgcn_s_waitcnt((n) | (7u << 4) | (15u << 8))

typedef __attribute__((address_space(1))) const void gas_void;
typedef __attribute__((address_space(3))) void las_void;

__global__ __launch_bounds__(256) void coscam_loss_kernel(
    const float* __restrict__ inputs,
    const int*   __restrict__ targets,
    const float* __restrict__ pos_mask,
    float*       __restrict__ out)
{
    const int row  = blockIdx.x;
    const int tid  = threadIdx.x;
    const int wave = tid >> 6;
    const int lane = tid & 63;

    // [wave][x|p][ring slot][256 floats] = 32 KB; each wave touches only its own region.
    __shared__ float stage[4][2][4][256];
    __shared__ float red_s[4];

    const float* __restrict__ rin = inputs   + (size_t)row * C_;
    const float* __restrict__ rpm = pos_mask + (size_t)row * C_;

    const int   t     = targets[row];
    const float gt    = rin[t];
    const float pos_t = rpm[t];

    const float wt      = gt - 0.1f;
    const float out_t   = 16.0f * wt;
    const float shift   = fmaxf(out_t, 40.0f);
    const float nshift2 = -shift * LOG2E;     // exp(16w - shift) = exp2(fma(w, 16log2e, nshift2))
    const float k16l2e  = 16.0f * LOG2E;

    // this wave's quarter of the row: 4096 floats = 16 chunks of 256
    const float* wx = rin + wave * 4096;
    const float* wp = rpm + wave * 4096;
    const int    lo = lane * 4;               // per-lane float offset within a chunk

    float acc0 = 0.0f, acc1 = 0.0f, acc2 = 0.0f, acc3 = 0.0f;

    // DMA one 1KB chunk pair: lane i fetches 16B at chunk + 16B*i,
    // HW writes LDS at slot_base + 16B*i (wave-uniform base + lane*size).
    auto issue = [&](int k) {
        __builtin_amdgcn_global_load_lds((gas_void*)(wx + (k << 8) + lo),
                                         (las_void*)&stage[wave][0][k & 3][0], 16, 0, 0);
        __builtin_amdgcn_global_load_lds((gas_void*)(wp + (k << 8) + lo),
                                         (las_void*)&stage[wave][1][k & 3][0], 16, 0, 0);
    };

    auto consume = [&](int k) {
        const float4 x4 = *(const float4*)&stage[wave][0][k & 3][lo];
        const float4 p4 = *(const float4*)&stage[wave][1][k & 3][lo];
        const float w0 = ((p4.x > 0.5f) && (x4.x >= gt)) ? fmaf(1.012f, x4.x, 0.012f) : x4.x;
        const float w1 = ((p4.y > 0.5f) && (x4.y >= gt)) ? fmaf(1.012f, x4.y, 0.012f) : x4.y;
        const float w2 = ((p4.z > 0.5f) && (x4.z >= gt)) ? fmaf(1.012f, x4.z, 0.012f) : x4.z;
        const float w3 = ((p4.w > 0.5f) && (x4.w >= gt)) ? fmaf(1.012f, x4.w, 0.012f) : x4.w;
        acc0 += __builtin_amdgcn_exp2f(fmaf(w0, k16l2e, nshift2));
        acc1 += __builtin_amdgcn_exp2f(fmaf(w1, k16l2e, nshift2));
        acc2 += __builtin_amdgcn_exp2f(fmaf(w2, k16l2e, nshift2));
        acc3 += __builtin_amdgcn_exp2f(fmaf(w3, k16l2e, nshift2));
    };

    // prologue: stages 0..3 in flight (8 DMAs)
    issue(0); issue(1); issue(2); issue(3);

    // steady state: wait for the oldest stage (<=6 outstanding => stage k landed),
    // consume it, refill its slot with stage k+4.
    #pragma unroll
    for (int k = 0; k < 12; ++k) {
        WAIT_VM(6);
        consume(k);
        issue(k + 4);
    }
    // tail: no more issues; thresholds tighten 6/4/2/0
    WAIT_VM(6); consume(12);
    WAIT_VM(4); consume(13);
    WAIT_VM(2); consume(14);
    WAIT_VM(0); consume(15);

    float s = (acc0 + acc1) + (acc2 + acc3);

    // wave-64 shuffle reduce
    #pragma unroll
    for (int off = 32; off > 0; off >>= 1)
        s += __shfl_down(s, off);

    if (lane == 0) red_s[wave] = s;
    __syncthreads();

    if (tid == 0) {
        float total = (red_s[0] + red_s[1]) + (red_s[2] + red_s[3]);
        // Exact correction for the target slot: loop used the generic formula
        // (x[t]==gt so hard-mask fired iff pos_t); replace that term with wt.
        const float w_wrong = (pos_t > 0.5f) ? fmaf(1.012f, gt, 0.012f) : gt;
        total += __builtin_amdgcn_exp2f(fmaf(wt,      k16l2e, nshift2))
               - __builtin_amdgcn_exp2f(fmaf(w_wrong, k16l2e, nshift2));
        const float loss_row = (__logf(total) + shift) - out_t;
        atomicAdd(out, loss_row * (1.0f / (float)B_));
    }
}

extern "C" void kernel_launch(void* const* d_in, const int* in_sizes, int n_in,
                              void* d_out, int out_size, void* d_ws, size_t ws_size,
                              hipStream_t stream) {
    const float* inputs   = (const float*)d_in[0];
    const int*   targets  = (const int*)  d_in[1];
    // d_in[2] = mask (unused by the reference)
    const float* pos_mask = (const float*)d_in[3];
    float* out = (float*)d_out;

    // d_out is poisoned 0xAA before every timed call -> zero it on-stream.
    (void)hipMemsetAsync(out, 0, sizeof(float), stream);

    coscam_loss_kernel<<<dim3(B_), dim3(256), 0, stream>>>(inputs, targets, pos_mask, out);
}